// Round 1
// baseline (6231.221 us; speedup 1.0000x reference)
//
#include <hip/hip_runtime.h>
#include <cstddef>

// LstmTl: N=64, L=128, D1=D2=H1=H2=64, 3 gates used (of 4 in weights).
// Phase 1: xg[l,g,n,a,b] = sum_ij Ww1[g,a,i] x[n,l,i,j] Ww2[g,b,j]  (full GPU)
// Phase 2: per-n persistent scan (64 WGs), h in LDS, c/z in registers.
//   c = r*(c+z); h = o*sigmoid(c)

#define DEV static __device__ __forceinline__

DEV float sigf(float x) { return 1.0f / (1.0f + __expf(-x)); }

DEV unsigned short f2bf(float f) {
  unsigned int u = __float_as_uint(f);
  u = (u + 0x7FFFu + ((u >> 16) & 1u)) >> 16;
  return (unsigned short)u;
}
DEV float bf2f(unsigned short s) { return __uint_as_float(((unsigned int)s) << 16); }

DEV void ld4(float v[4], const float* p) {
  float4 t = *(const float4*)p;
  v[0] = t.x; v[1] = t.y; v[2] = t.z; v[3] = t.w;
}

// acc[r][c] += sum_k A[k*64 + a0+r] * B[k*64 + b0+c]
// A and B are k-major (transposed weights / LDS tiles) so both are float4 loads.
DEV void mm_acc(float acc[4][4], const float* A, const float* B, int a0, int b0) {
#pragma unroll 8
  for (int k = 0; k < 64; ++k) {
    float av[4], bv[4];
    ld4(av, A + k * 64 + a0);
    ld4(bv, B + k * 64 + b0);
#pragma unroll
    for (int r = 0; r < 4; ++r)
#pragma unroll
      for (int c = 0; c < 4; ++c)
        acc[r][c] = __fmaf_rn(av[r], bv[c], acc[r][c]);
  }
}

// store acc tile transposed: Tt[j][a] = acc[a][j]  (so next matmul reads k-major)
DEV void wr_tt(float* Tt, const float acc[4][4], int a0, int b0) {
#pragma unroll
  for (int c = 0; c < 4; ++c)
    *(float4*)(Tt + (b0 + c) * 64 + a0) =
        make_float4(acc[0][c], acc[1][c], acc[2][c], acc[3][c]);
}

// ---------------- weight transpose: WT layout [mat(4)][g(3)][k(64)][a(64)] ----
__global__ __launch_bounds__(256) void wtrans_kernel(
    const float* __restrict__ Ww1, const float* __restrict__ Ww2,
    const float* __restrict__ Wu1, const float* __restrict__ Wu2,
    float* __restrict__ o) {
  int b = blockIdx.x;  // 0..11 = mat*3+g
  int mat = b / 3, g = b % 3;
  const float* src =
      (mat == 0 ? Ww1 : mat == 1 ? Ww2 : mat == 2 ? Wu1 : Wu2) + g * 4096;
  float* dst = o + b * 4096;
  for (int e = threadIdx.x; e < 4096; e += 256) {
    int a = e >> 6, i = e & 63;
    dst[i * 64 + a] = src[a * 64 + i];
  }
}

// ---------------- phase 1: xg precompute --------------------------------------
template <bool BF16>
__global__ __launch_bounds__(256) void xg_kernel(
    const float* __restrict__ x, const float* __restrict__ WT,
    void* __restrict__ xg_out) {
  __shared__ float xt[4096];
  __shared__ float Tt[4096];
  const int n = blockIdx.x, g = blockIdx.y, l = blockIdx.z;
  const int tid = threadIdx.x;
  const int a0 = (tid >> 4) << 2;
  const int b0 = (tid & 15) << 2;
  const float4* src = (const float4*)(x + (((size_t)n * 128 + l) << 12));
#pragma unroll
  for (int e = 0; e < 4; ++e) ((float4*)xt)[tid + 256 * e] = src[tid + 256 * e];
  __syncthreads();
  float acc[4][4] = {};
  mm_acc(acc, WT + g * 4096, xt, a0, b0);  // T = Ww1[g] @ x
  wr_tt(Tt, acc, a0, b0);
  __syncthreads();
  float acc2[4][4] = {};
  mm_acc(acc2, Tt, WT + (3 + g) * 4096, a0, b0);  // xg = T @ Ww2[g]^T
  const size_t base = (((size_t)l * 3 + g) * 64 + n) << 12;
#pragma unroll
  for (int r = 0; r < 4; ++r) {
    if constexpr (BF16) {
      ushort4 u;
      u.x = f2bf(acc2[r][0]); u.y = f2bf(acc2[r][1]);
      u.z = f2bf(acc2[r][2]); u.w = f2bf(acc2[r][3]);
      *(ushort4*)((unsigned short*)xg_out + base + (a0 + r) * 64 + b0) = u;
    } else {
      *(float4*)((float*)xg_out + base + (a0 + r) * 64 + b0) =
          make_float4(acc2[r][0], acc2[r][1], acc2[r][2], acc2[r][3]);
    }
  }
}

// ---------------- phase 2: per-n recurrence -----------------------------------
template <int MODE>
DEV void load_xg(float gv[4][4], const void* xg_in, size_t base, int a0, int b0) {
#pragma unroll
  for (int r = 0; r < 4; ++r) {
    if constexpr (MODE == 0) {
      ld4(gv[r], (const float*)xg_in + base + (a0 + r) * 64 + b0);
    } else {
      ushort4 u = *(const ushort4*)((const unsigned short*)xg_in + base +
                                    (a0 + r) * 64 + b0);
      gv[r][0] = bf2f(u.x); gv[r][1] = bf2f(u.y);
      gv[r][2] = bf2f(u.z); gv[r][3] = bf2f(u.w);
    }
  }
}

// gv = xg[l,g,n] + Wu1[g] @ h @ Wu2[g]^T   (tile owned by this thread)
template <int MODE>
DEV void gate_mm(float gv[4][4], int l, int g, int n, int a0, int b0,
                 const float* WT, const void* xg_in, const float* xt,
                 float* hs, float* Tt) {
  if constexpr (MODE == 2) {  // compute xg on the fly (small-ws fallback)
    float accx[4][4] = {};
    mm_acc(accx, WT + g * 4096, xt, a0, b0);
    wr_tt(Tt, accx, a0, b0);
    __syncthreads();
#pragma unroll
    for (int r = 0; r < 4; ++r)
#pragma unroll
      for (int c = 0; c < 4; ++c) gv[r][c] = 0.0f;
    mm_acc(gv, Tt, WT + (3 + g) * 4096, a0, b0);
    __syncthreads();
  } else {
    const size_t base = (((size_t)l * 3 + g) * 64 + n) << 12;
    load_xg<MODE>(gv, xg_in, base, a0, b0);
  }
  float acc[4][4] = {};
  mm_acc(acc, WT + (6 + g) * 4096, hs, a0, b0);  // T = Wu1[g] @ h
  wr_tt(Tt, acc, a0, b0);
  __syncthreads();
  mm_acc(gv, Tt, WT + (9 + g) * 4096, a0, b0);   // gv += T @ Wu2[g]^T
}

template <int MODE>
__global__ __launch_bounds__(256) void rec_kernel(
    const float* __restrict__ WT, const void* __restrict__ xg_in,
    const float* __restrict__ inputs, float* __restrict__ out) {
  __shared__ float hs[4096];
  __shared__ float Tt[4096];
  __shared__ float xt[(MODE == 2) ? 4096 : 4];
  const int n = blockIdx.x;
  const int tid = threadIdx.x;
  const int a0 = (tid >> 4) << 2;
  const int b0 = (tid & 15) << 2;
  float creg[4][4] = {};  // c lives in registers (tile owned by this thread)
  float zreg[4][4];
  float hnew[4][4] = {};
  for (int e = tid; e < 4096; e += 256) hs[e] = 0.0f;
  __syncthreads();
  for (int l = 0; l < 128; ++l) {
    if constexpr (MODE == 2) {
      const float4* src = (const float4*)(inputs + (((size_t)n * 128 + l) << 12));
#pragma unroll
      for (int e = 0; e < 4; ++e)
        ((float4*)xt)[tid + 256 * e] = src[tid + 256 * e];
      __syncthreads();
    }
    float gv[4][4];

    // gate 0: z
    gate_mm<MODE>(gv, l, 0, n, a0, b0, WT, xg_in, xt, hs, Tt);
#pragma unroll
    for (int r = 0; r < 4; ++r)
#pragma unroll
      for (int c = 0; c < 4; ++c) zreg[r][c] = sigf(gv[r][c]);
    __syncthreads();

    // gate 1: r ;  c = r*(c+z)
    gate_mm<MODE>(gv, l, 1, n, a0, b0, WT, xg_in, xt, hs, Tt);
#pragma unroll
    for (int r = 0; r < 4; ++r)
#pragma unroll
      for (int c = 0; c < 4; ++c) {
        float rr = sigf(gv[r][c]);
        creg[r][c] = rr * (creg[r][c] + zreg[r][c]);
      }
    __syncthreads();

    // gate 2: o ;  h = o*sig(c) ; write h to LDS + out
    gate_mm<MODE>(gv, l, 2, n, a0, b0, WT, xg_in, xt, hs, Tt);
    float* op = out + (((size_t)n * 128 + l) << 12);
#pragma unroll
    for (int r = 0; r < 4; ++r) {
#pragma unroll
      for (int c = 0; c < 4; ++c)
        hnew[r][c] = sigf(gv[r][c]) * sigf(creg[r][c]);
      float4 v = make_float4(hnew[r][0], hnew[r][1], hnew[r][2], hnew[r][3]);
      *(float4*)(hs + (a0 + r) * 64 + b0) = v;
      *(float4*)(op + (a0 + r) * 64 + b0) = v;
    }
    __syncthreads();
  }
  // h_last, c_last
  float* hl = out + 33554432 + ((size_t)n << 12);
  float* cl = hl + 262144;
#pragma unroll
  for (int r = 0; r < 4; ++r) {
    *(float4*)(hl + (a0 + r) * 64 + b0) =
        make_float4(hnew[r][0], hnew[r][1], hnew[r][2], hnew[r][3]);
    *(float4*)(cl + (a0 + r) * 64 + b0) =
        make_float4(creg[r][0], creg[r][1], creg[r][2], creg[r][3]);
  }
}

extern "C" void kernel_launch(void* const* d_in, const int* in_sizes, int n_in,
                              void* d_out, int out_size, void* d_ws,
                              size_t ws_size, hipStream_t stream) {
  (void)in_sizes; (void)n_in; (void)out_size;
  const float* inputs = (const float*)d_in[0];
  const float* Ww1 = (const float*)d_in[1];
  const float* Ww2 = (const float*)d_in[2];
  const float* Wu1 = (const float*)d_in[3];
  const float* Wu2 = (const float*)d_in[4];
  float* out = (float*)d_out;
  char* ws = (char*)d_ws;
  float* WT = (float*)ws;                 // 12 * 4096 f32 = 196,608 B
  const size_t XG_OFF = 262144;
  void* xg = (void*)(ws + XG_OFF);
  const size_t XG_F32 = (size_t)128 * 3 * 64 * 4096 * 4;  // 402,653,184 B
  const size_t XG_BF16 = XG_F32 / 2;

  wtrans_kernel<<<dim3(12), dim3(256), 0, stream>>>(Ww1, Ww2, Wu1, Wu2, WT);

  if (ws_size >= XG_OFF + XG_F32) {
    xg_kernel<false><<<dim3(64, 3, 128), dim3(256), 0, stream>>>(inputs, WT, xg);
    rec_kernel<0><<<dim3(64), dim3(256), 0, stream>>>(WT, xg, inputs, out);
  } else if (ws_size >= XG_OFF + XG_BF16) {
    xg_kernel<true><<<dim3(64, 3, 128), dim3(256), 0, stream>>>(inputs, WT, xg);
    rec_kernel<1><<<dim3(64), dim3(256), 0, stream>>>(WT, xg, inputs, out);
  } else {
    rec_kernel<2><<<dim3(64), dim3(256), 0, stream>>>(WT, nullptr, inputs, out);
  }
}

// Round 3
// 994.708 us; speedup vs baseline: 6.2644x; 6.2644x over previous
//
#include <hip/hip_runtime.h>
#include <cstddef>

#define DEV static __device__ __forceinline__

typedef __attribute__((ext_vector_type(8))) short bf16x8;
typedef __attribute__((ext_vector_type(4))) float f32x4;

#define MFMA __builtin_amdgcn_mfma_f32_16x16x32_bf16

DEV float sigf(float x) { return 1.0f / (1.0f + __expf(-x)); }

DEV unsigned short f2bf(float f) {
  unsigned int u = __float_as_uint(f);
  u = (u + 0x7FFFu + ((u >> 16) & 1u)) >> 16;
  return (unsigned short)u;
}
DEV float bf2f(unsigned short s) { return __uint_as_float(((unsigned int)s) << 16); }
DEV void split_bf(float v, unsigned short& hi, unsigned short& lo) {
  hi = f2bf(v);
  lo = f2bf(v - bf2f(hi));
}

// packed-fragment load: 16B per lane, conflict-free (addr = lane*16 + const)
DEV bf16x8 ldpk(const unsigned short* buf, int chunk, int lane) {
  return *(const bf16x8*)(buf + (chunk * 64 + lane) * 8);
}
// col-major XOR-swizzled buffer (h, x): element (k, col) at byte col*128+k*2
DEV bf16x8 ldB(const unsigned short* buf, int col, int k0) {
  int byte = (col * 128 + k0 * 2) ^ ((col & 7) << 4);
  return *(const bf16x8*)((const char*)buf + byte);
}
// row-major XOR-swizzled buffer (T): element (row, k) at byte row*128+k*2
DEV bf16x8 ldA(const unsigned short* buf, int row, int k0) {
  int byte = (row * 128 + k0 * 2) ^ ((row & 7) << 4);
  return *(const bf16x8*)((const char*)buf + byte);
}
DEV void stB4(unsigned short* buf, int col, int k0, const unsigned short v[4]) {
  int byte = (col * 128 + k0 * 2) ^ ((col & 7) << 4);
  *(ushort4*)((char*)buf + byte) = make_ushort4(v[0], v[1], v[2], v[3]);
}
DEV void stA1(unsigned short* buf, int row, int k, unsigned short v) {
  int byte = (row * 128 + k * 2) ^ ((row & 7) << 4);
  *(unsigned short*)((char*)buf + byte) = v;
}

// ---- pack kernel: split each 64x64 weight into bf16 hi/lo, fragment order ----
// pk layout: [(mat*3+g)*2 + half][4096 ushort]; frag elem: lane l of chunk
// (rb*2+kc) holds W[rb*16 + l%16][kc*32 + (l/16)*8 + j], j=0..7
__global__ __launch_bounds__(256) void pack_kernel(
    const float* __restrict__ Ww1, const float* __restrict__ Ww2,
    const float* __restrict__ Wu1, const float* __restrict__ Wu2,
    unsigned short* __restrict__ pk) {
  int b = blockIdx.x;  // 0..11 = mat*3+g
  int mat = b / 3, g = b % 3;
  const float* src =
      (mat == 0 ? Ww1 : mat == 1 ? Ww2 : mat == 2 ? Wu1 : Wu2) + g * 4096;
  unsigned short* dhi = pk + (b * 2 + 0) * 4096;
  unsigned short* dlo = pk + (b * 2 + 1) * 4096;
  for (int idx = threadIdx.x; idx < 4096; idx += 256) {
    int chunk = idx >> 9;
    int lane = (idx >> 3) & 63;
    int j = idx & 7;
    int row = (chunk >> 1) * 16 + (lane & 15);
    int k = (chunk & 1) * 32 + (lane >> 4) * 8 + j;
    unsigned short hi, lo;
    split_bf(src[row * 64 + k], hi, lo);
    dhi[idx] = hi;
    dlo[idx] = lo;
  }
}

// ---- phase 1: xg[l,g,n,a,b] = (Ww1[g] @ x_nl) @ Ww2[g]^T, f32 out -----------
__global__ __launch_bounds__(256, 2) void xg_mfma_kernel(
    const float* __restrict__ x, const unsigned short* __restrict__ pk,
    float* __restrict__ xg) {
  __shared__ unsigned short xS[2][4096];
  __shared__ unsigned short tS[2][4096];
  const int n = blockIdx.x, l = blockIdx.y;
  const int tid = threadIdx.x;
  const int lane = tid & 63, mi = tid >> 6;
  const int lrow = lane & 15, lkg = lane >> 4;
  const f32x4 zero = {0.f, 0.f, 0.f, 0.f};

  const float* xp = x + (((size_t)n * 128 + l) << 12);
  for (int i = tid; i < 1024; i += 256) {
    float4 v = ((const float4*)xp)[i];
    int row = i >> 4, cb = (i & 15) * 4;
    float vv[4] = {v.x, v.y, v.z, v.w};
#pragma unroll
    for (int j = 0; j < 4; ++j) {
      unsigned short hi, lo;
      split_bf(vv[j], hi, lo);
      int byte = ((cb + j) * 128 + row * 2) ^ (((cb + j) & 7) << 4);
      *(unsigned short*)((char*)xS[0] + byte) = hi;
      *(unsigned short*)((char*)xS[1] + byte) = lo;
    }
  }
  __syncthreads();

  for (int g = 0; g < 3; ++g) {
    const unsigned short* w1h = pk + (g * 2 + 0) * 4096;
    const unsigned short* w1l = pk + (g * 2 + 1) * 4096;
    const unsigned short* w2h = pk + ((3 + g) * 2 + 0) * 4096;
    const unsigned short* w2l = pk + ((3 + g) * 2 + 1) * 4096;
    f32x4 ac[4];
#pragma unroll
    for (int t = 0; t < 4; ++t) ac[t] = zero;
#pragma unroll
    for (int kc = 0; kc < 2; ++kc) {
      const int k0 = kc * 32 + lkg * 8;
      bf16x8 wh = ldpk(w1h, mi * 2 + kc, lane);
      bf16x8 wl = ldpk(w1l, mi * 2 + kc, lane);
#pragma unroll
      for (int t = 0; t < 4; ++t) {
        bf16x8 bh = ldB(xS[0], t * 16 + lrow, k0);
        bf16x8 bl = ldB(xS[1], t * 16 + lrow, k0);
        ac[t] = MFMA(wh, bh, ac[t], 0, 0, 0);
        ac[t] = MFMA(wl, bh, ac[t], 0, 0, 0);
        ac[t] = MFMA(wh, bl, ac[t], 0, 0, 0);
      }
    }
#pragma unroll
    for (int t = 0; t < 4; ++t)
#pragma unroll
      for (int r = 0; r < 4; ++r) {
        unsigned short hi, lo;
        split_bf(ac[t][r], hi, lo);
        stA1(tS[0], mi * 16 + lkg * 4 + r, t * 16 + lrow, hi);
        stA1(tS[1], mi * 16 + lkg * 4 + r, t * 16 + lrow, lo);
      }
    __syncthreads();
    f32x4 qc[4];
#pragma unroll
    for (int t = 0; t < 4; ++t) qc[t] = zero;
#pragma unroll
    for (int kc = 0; kc < 2; ++kc) {
      const int k0 = kc * 32 + lkg * 8;
      bf16x8 th = ldA(tS[0], mi * 16 + lrow, k0);
      bf16x8 tl = ldA(tS[1], mi * 16 + lrow, k0);
#pragma unroll
      for (int t = 0; t < 4; ++t) {
        bf16x8 bh = ldpk(w2h, t * 2 + kc, lane);
        bf16x8 bl = ldpk(w2l, t * 2 + kc, lane);
        qc[t] = MFMA(th, bh, qc[t], 0, 0, 0);
        qc[t] = MFMA(tl, bh, qc[t], 0, 0, 0);
        qc[t] = MFMA(th, bl, qc[t], 0, 0, 0);
      }
    }
    float* xo = xg + (((size_t)l * 3 + g) * 64 + n) * 4096;
#pragma unroll
    for (int t = 0; t < 4; ++t)
#pragma unroll
      for (int r = 0; r < 4; ++r)
        xo[(mi * 16 + lkg * 4 + r) * 64 + t * 16 + lrow] = qc[t][r];
    __syncthreads();
  }
}

// ---- phase 2: per-n persistent recurrence, MFMA split-bf16 -------------------
__global__ __launch_bounds__(512, 2) void rec_mfma_kernel(
    const unsigned short* __restrict__ pk, const float* __restrict__ xg,
    float* __restrict__ out) {
  __shared__ unsigned short u1[3][2][4096];  // Wu1 packed frags (hi/lo)
  __shared__ unsigned short u2[3][2][4096];  // Wu2 packed frags (hi/lo)
  __shared__ unsigned short hS[2][4096];     // h split, col-major swz
  __shared__ unsigned short tS[2][2][4096];  // T split, row-major swz, dbuf
  const int n = blockIdx.x;
  const int tid = threadIdx.x;
  const int lane = tid & 63, wave = tid >> 6;
  const int mi = wave >> 1, nb = (wave & 1) * 2;  // tiles (mi, nb), (mi, nb+1)
  const int lrow = lane & 15, lkg = lane >> 4;
  const f32x4 zero = {0.f, 0.f, 0.f, 0.f};

  {  // copy Wu1/Wu2 packed frags (96KB) into LDS; zero h
    const float4* s1 = (const float4*)(pk + 12 * 4096);
    const float4* s2 = (const float4*)(pk + 18 * 4096);
    float4* d1 = (float4*)u1;
    float4* d2 = (float4*)u2;
    for (int i = tid; i < 3072; i += 512) {
      d1[i] = s1[i];
      d2[i] = s2[i];
    }
    for (int i = tid; i < 4096; i += 512) {
      hS[0][i] = 0;
      hS[1][i] = 0;
    }
  }
  __syncthreads();

  float c[2][4] = {}, z[2][4], hn[2][4] = {};

#pragma unroll 1
  for (int l = 0; l < 128; ++l) {
    // prefetch this step's xg tiles into registers (overlaps gate-0 matmul1)
    float xv[3][2][4];
    const float* xb = xg + (((size_t)l * 3) * 64 + n) * 4096;
#pragma unroll
    for (int g = 0; g < 3; ++g)
#pragma unroll
      for (int t = 0; t < 2; ++t)
#pragma unroll
        for (int r = 0; r < 4; ++r)
          xv[g][t][r] = xb[(size_t)g * 262144 + (mi * 16 + lkg * 4 + r) * 64 +
                           (nb + t) * 16 + lrow];

#pragma unroll
    for (int g = 0; g < 3; ++g) {
      unsigned short* tb0 = (g == 1) ? tS[1][0] : tS[0][0];
      unsigned short* tb1 = (g == 1) ? tS[1][1] : tS[0][1];
      // matmul1: T = Wu1[g] @ h   (split: hh + lh + hl)
      f32x4 a0 = zero, a1 = zero;
#pragma unroll
      for (int kc = 0; kc < 2; ++kc) {
        const int k0 = kc * 32 + lkg * 8;
        bf16x8 wh = ldpk(u1[g][0], mi * 2 + kc, lane);
        bf16x8 wl = ldpk(u1[g][1], mi * 2 + kc, lane);
        bf16x8 b0h = ldB(hS[0], nb * 16 + lrow, k0);
        bf16x8 b0l = ldB(hS[1], nb * 16 + lrow, k0);
        bf16x8 b1h = ldB(hS[0], (nb + 1) * 16 + lrow, k0);
        bf16x8 b1l = ldB(hS[1], (nb + 1) * 16 + lrow, k0);
        a0 = MFMA(wh, b0h, a0, 0, 0, 0);
        a1 = MFMA(wh, b1h, a1, 0, 0, 0);
        a0 = MFMA(wl, b0h, a0, 0, 0, 0);
        a1 = MFMA(wl, b1h, a1, 0, 0, 0);
        a0 = MFMA(wh, b0l, a0, 0, 0, 0);
        a1 = MFMA(wh, b1l, a1, 0, 0, 0);
      }
      // split-write T
#pragma unroll
      for (int t = 0; t < 2; ++t)
#pragma unroll
        for (int r = 0; r < 4; ++r) {
          unsigned short hi, lo;
          split_bf(t ? a1[r] : a0[r], hi, lo);
          int row = mi * 16 + lkg * 4 + r;
          int k = (nb + t) * 16 + lrow;
          stA1(tb0, row, k, hi);
          stA1(tb1, row, k, lo);
        }
      __syncthreads();
      // matmul2: G = T @ Wu2[g]^T
      f32x4 q0 = zero, q1 = zero;
#pragma unroll
      for (int kc = 0; kc < 2; ++kc) {
        const int k0 = kc * 32 + lkg * 8;
        bf16x8 th = ldA(tb0, mi * 16 + lrow, k0);
        bf16x8 tl = ldA(tb1, mi * 16 + lrow, k0);
        bf16x8 c0h = ldpk(u2[g][0], (nb + 0) * 2 + kc, lane);
        bf16x8 c0l = ldpk(u2[g][1], (nb + 0) * 2 + kc, lane);
        bf16x8 c1h = ldpk(u2[g][0], (nb + 1) * 2 + kc, lane);
        bf16x8 c1l = ldpk(u2[g][1], (nb + 1) * 2 + kc, lane);
        q0 = MFMA(th, c0h, q0, 0, 0, 0);
        q1 = MFMA(th, c1h, q1, 0, 0, 0);
        q0 = MFMA(tl, c0h, q0, 0, 0, 0);
        q1 = MFMA(tl, c1h, q1, 0, 0, 0);
        q0 = MFMA(th, c0l, q0, 0, 0, 0);
        q1 = MFMA(th, c1l, q1, 0, 0, 0);
      }
      // epilogue
      if (g == 0) {
#pragma unroll
        for (int t = 0; t < 2; ++t)
#pragma unroll
          for (int r = 0; r < 4; ++r)
            z[t][r] = sigf((t ? q1[r] : q0[r]) + xv[0][t][r]);
      } else if (g == 1) {
#pragma unroll
        for (int t = 0; t < 2; ++t)
#pragma unroll
          for (int r = 0; r < 4; ++r) {
            float rr = sigf((t ? q1[r] : q0[r]) + xv[1][t][r]);
            c[t][r] = rr * (c[t][r] + z[t][r]);  // c = r*c + z*r
          }
      } else {
        float* op = out + (((size_t)n * 128 + l) << 12);
#pragma unroll
        for (int t = 0; t < 2; ++t) {
          unsigned short hh[4], hl[4];
#pragma unroll
          for (int r = 0; r < 4; ++r) {
            float o = sigf((t ? q1[r] : q0[r]) + xv[2][t][r]);
            hn[t][r] = o * sigf(c[t][r]);
            split_bf(hn[t][r], hh[r], hl[r]);
            op[(mi * 16 + lkg * 4 + r) * 64 + (nb + t) * 16 + lrow] = hn[t][r];
          }
          stB4(hS[0], (nb + t) * 16 + lrow, mi * 16 + lkg * 4, hh);
          stB4(hS[1], (nb + t) * 16 + lrow, mi * 16 + lkg * 4, hl);
        }
      }
    }
    __syncthreads();  // h visible for next step; tS[0] reusable
  }
  // h_last, c_last
  float* hl_ = out + 33554432 + ((size_t)n << 12);
  float* cl_ = hl_ + 262144;
#pragma unroll
  for (int t = 0; t < 2; ++t)
#pragma unroll
    for (int r = 0; r < 4; ++r) {
      int off = (mi * 16 + lkg * 4 + r) * 64 + (nb + t) * 16 + lrow;
      hl_[off] = hn[t][r];
      cl_[off] = c[t][r];
    }
}

// ---- fallback (ws too small): old f32 VALU path ------------------------------
DEV void ld4(float v[4], const float* p) {
  float4 t = *(const float4*)p;
  v[0] = t.x; v[1] = t.y; v[2] = t.z; v[3] = t.w;
}
DEV void mm_acc(float acc[4][4], const float* A, const float* B, int a0, int b0) {
#pragma unroll 8
  for (int k = 0; k < 64; ++k) {
    float av[4], bv[4];
    ld4(av, A + k * 64 + a0);
    ld4(bv, B + k * 64 + b0);
#pragma unroll
    for (int r = 0; r < 4; ++r)
#pragma unroll
      for (int cc = 0; cc < 4; ++cc)
        acc[r][cc] = __fmaf_rn(av[r], bv[cc], acc[r][cc]);
  }
}
DEV void wr_tt(float* Tt, const float acc[4][4], int a0, int b0) {
#pragma unroll
  for (int cc = 0; cc < 4; ++cc)
    *(float4*)(Tt + (b0 + cc) * 64 + a0) =
        make_float4(acc[0][cc], acc[1][cc], acc[2][cc], acc[3][cc]);
}
__global__ __launch_bounds__(256) void wtrans_kernel(
    const float* __restrict__ Ww1, const float* __restrict__ Ww2,
    const float* __restrict__ Wu1, const float* __restrict__ Wu2,
    float* __restrict__ o) {
  int b = blockIdx.x;
  int mat = b / 3, g = b % 3;
  const float* src =
      (mat == 0 ? Ww1 : mat == 1 ? Ww2 : mat == 2 ? Wu1 : Wu2) + g * 4096;
  float* dst = o + b * 4096;
  for (int e = threadIdx.x; e < 4096; e += 256) {
    int a = e >> 6, i = e & 63;
    dst[i * 64 + a] = src[a * 64 + i];
  }
}
__global__ __launch_bounds__(256) void rec_fb_kernel(
    const float* __restrict__ WT, const float* __restrict__ inputs,
    float* __restrict__ out) {
  __shared__ float hs[4096];
  __shared__ float Tt[4096];
  __shared__ float xt[4096];
  const int n = blockIdx.x;
  const int tid = threadIdx.x;
  const int a0 = (tid >> 4) << 2;
  const int b0 = (tid & 15) << 2;
  float creg[4][4] = {}, zreg[4][4], hnew[4][4] = {};
  for (int e = tid; e < 4096; e += 256) hs[e] = 0.0f;
  __syncthreads();
  for (int l = 0; l < 128; ++l) {
    const float4* src = (const float4*)(inputs + (((size_t)n * 128 + l) << 12));
#pragma unroll
    for (int e = 0; e < 4; ++e)
      ((float4*)xt)[tid + 256 * e] = src[tid + 256 * e];
    __syncthreads();
    for (int g = 0; g < 3; ++g) {
      float gv[4][4] = {};
      float accx[4][4] = {};
      mm_acc(accx, WT + g * 4096, xt, a0, b0);
      wr_tt(Tt, accx, a0, b0);
      __syncthreads();
      mm_acc(gv, Tt, WT + (3 + g) * 4096, a0, b0);
      __syncthreads();
      float acc[4][4] = {};
      mm_acc(acc, WT + (6 + g) * 4096, hs, a0, b0);
      wr_tt(Tt, acc, a0, b0);
      __syncthreads();
      mm_acc(gv, Tt, WT + (9 + g) * 4096, a0, b0);
      if (g == 0) {
#pragma unroll
        for (int r = 0; r < 4; ++r)
#pragma unroll
          for (int cc = 0; cc < 4; ++cc) zreg[r][cc] = sigf(gv[r][cc]);
      } else if (g == 1) {
#pragma unroll
        for (int r = 0; r < 4; ++r)
#pragma unroll
          for (int cc = 0; cc < 4; ++cc) {
            float rr = sigf(gv[r][cc]);
            creg[r][cc] = rr * (creg[r][cc] + zreg[r][cc]);
          }
      } else {
        float* op = out + (((size_t)n * 128 + l) << 12);
#pragma unroll
        for (int r = 0; r < 4; ++r) {
#pragma unroll
          for (int cc = 0; cc < 4; ++cc)
            hnew[r][cc] = sigf(gv[r][cc]) * sigf(creg[r][cc]);
          float4 v = make_float4(hnew[r][0], hnew[r][1], hnew[r][2], hnew[r][3]);
          *(float4*)(hs + (a0 + r) * 64 + b0) = v;
          *(float4*)(op + (a0 + r) * 64 + b0) = v;
        }
      }
      __syncthreads();
    }
  }
  float* hl = out + 33554432 + ((size_t)n << 12);
  float* cl = hl + 262144;
#pragma unroll
  for (int r = 0; r < 4; ++r) {
    *(float4*)(hl + (a0 + r) * 64 + b0) =
        make_float4(hnew[r][0], hnew[r][1], hnew[r][2], hnew[r][3]);
    *(float4*)(cl + (a0 + r) * 64 + b0) =
        make_float4(creg[r][0], creg[r][1], creg[r][2], creg[r][3]);
  }
}

extern "C" void kernel_launch(void* const* d_in, const int* in_sizes, int n_in,
                              void* d_out, int out_size, void* d_ws,
                              size_t ws_size, hipStream_t stream) {
  (void)in_sizes; (void)n_in; (void)out_size;
  const float* inputs = (const float*)d_in[0];
  const float* Ww1 = (const float*)d_in[1];
  const float* Ww2 = (const float*)d_in[2];
  const float* Wu1 = (const float*)d_in[3];
  const float* Wu2 = (const float*)d_in[4];
  float* out = (float*)d_out;
  char* ws = (char*)d_ws;
  const size_t XG_OFF = 262144;
  const size_t XG_F32 = (size_t)128 * 3 * 64 * 4096 * 4;  // 402,653,184 B

  if (ws_size >= XG_OFF + XG_F32) {
    unsigned short* pk = (unsigned short*)ws;
    float* xg = (float*)(ws + XG_OFF);
    pack_kernel<<<dim3(12), dim3(256), 0, stream>>>(Ww1, Ww2, Wu1, Wu2, pk);
    xg_mfma_kernel<<<dim3(64, 128), dim3(256), 0, stream>>>(inputs, pk, xg);
    rec_mfma_kernel<<<dim3(64), dim3(512), 0, stream>>>(pk, xg, out);
  } else {
    float* WT = (float*)ws;
    wtrans_kernel<<<dim3(12), dim3(256), 0, stream>>>(Ww1, Ww2, Wu1, Wu2, WT);
    rec_fb_kernel<<<dim3(64), dim3(256), 0, stream>>>(WT, inputs, out);
  }
}

// Round 4
// 928.830 us; speedup vs baseline: 6.7087x; 1.0709x over previous
//
#include <hip/hip_runtime.h>
#include <hip/hip_bf16.h>
#include <cstddef>

#define DEV static __device__ __forceinline__

typedef __attribute__((ext_vector_type(8))) short bf16x8;
typedef __attribute__((ext_vector_type(4))) float f32x4;

#define MFMA32 __builtin_amdgcn_mfma_f32_16x16x32_bf16

DEV float sigf(float x) { return 1.0f / (1.0f + __expf(-x)); }

DEV unsigned short f2bf(float f) {
  unsigned int u = __float_as_uint(f);
  u = (u + 0x7FFFu + ((u >> 16) & 1u)) >> 16;
  return (unsigned short)u;
}
DEV float bf2f(unsigned short s) { return __uint_as_float(((unsigned int)s) << 16); }
DEV void split_bf(float v, unsigned short& hi, unsigned short& lo) {
  hi = f2bf(v);
  lo = f2bf(v - bf2f(hi));
}
DEV unsigned int pk2(float lo, float hi) {
  __hip_bfloat162 t = __float22bfloat162_rn(make_float2(lo, hi));
  union { __hip_bfloat162 h; unsigned int u; } x;
  x.h = t;
  return x.u;
}
DEV bf16x8 frag4(unsigned int a, unsigned int b, unsigned int c,
                 unsigned int d) {
  union { unsigned int u[4]; bf16x8 v; } x;
  x.u[0] = a; x.u[1] = b; x.u[2] = c; x.u[3] = d;
  return x.v;
}

// packed-fragment load: 16B per lane, conflict-free (addr = lane*16 + const)
DEV bf16x8 ldpk(const unsigned short* buf, int chunk, int lane) {
  return *(const bf16x8*)(buf + (chunk * 64 + lane) * 8);
}
// col-major XOR-swizzled buffer (h^T / x^T source): element (k,col) at byte
// col*128 + k*2, swizzled.
DEV bf16x8 ldB(const unsigned short* buf, int col, int k0) {
  int byte = (col * 128 + k0 * 2) ^ ((col & 7) << 4);
  return *(const bf16x8*)((const char*)buf + byte);
}
DEV void stB4(unsigned short* buf, int col, int k0, const unsigned short v[4]) {
  int byte = (col * 128 + k0 * 2) ^ ((col & 7) << 4);
  *(ushort4*)((char*)buf + byte) = make_ushort4(v[0], v[1], v[2], v[3]);
}

// ---- pack kernel -------------------------------------------------------------
// pkA (x32 frag layout, as verified in R3): b = m3*6 + g*2 + half, m3: 0=Ww1,
//   1=Wu1. chunk rb*2+kc: lane l, j: W[rb*16 + (l&15)][kc*32 + (l>>4)*8 + j].
// pkB (x16-relabel layout for matmul2 B-operand): b = m3*6 + g*2 + half,
//   m3: 0=Ww2, 1=Wu2. chunk bt*2+jc: lane l, jj:
//   W[bt*16 + (l&15)][32*jc + 16*(jj>>2) + 4*(l>>4) + (jj&3)].
__global__ __launch_bounds__(256) void pack2_kernel(
    const float* __restrict__ Ww1, const float* __restrict__ Ww2,
    const float* __restrict__ Wu1, const float* __restrict__ Wu2,
    unsigned short* __restrict__ pkA, unsigned short* __restrict__ pkB) {
  int b = blockIdx.x;  // 0..23
  if (b < 12) {
    int m3 = b / 6, rem = b % 6, g = rem >> 1, half = rem & 1;
    const float* src = (m3 ? Wu1 : Ww1) + g * 4096;
    unsigned short* dst = pkA + b * 4096;
    for (int idx = threadIdx.x; idx < 4096; idx += 256) {
      int chunk = idx >> 9, lane = (idx >> 3) & 63, jj = idx & 7;
      int row = (chunk >> 1) * 16 + (lane & 15);
      int k = (chunk & 1) * 32 + (lane >> 4) * 8 + jj;
      unsigned short hi, lo;
      split_bf(src[row * 64 + k], hi, lo);
      dst[idx] = half ? lo : hi;
    }
  } else {
    int bb = b - 12;
    int m3 = bb / 6, rem = bb % 6, g = rem >> 1, half = rem & 1;
    const float* src = (m3 ? Wu2 : Ww2) + g * 4096;
    unsigned short* dst = pkB + bb * 4096;
    for (int idx = threadIdx.x; idx < 4096; idx += 256) {
      int chunk = idx >> 9, lane = (idx >> 3) & 63, jj = idx & 7;
      int bcol = (chunk >> 1) * 16 + (lane & 15);
      int j = 32 * (chunk & 1) + 16 * (jj >> 2) + 4 * (lane >> 4) + (jj & 3);
      unsigned short hi, lo;
      split_bf(src[bcol * 64 + j], hi, lo);
      dst[idx] = half ? lo : hi;
    }
  }
}

// Shared core: given S^T-fragments (h^T or x^T, hi/lo, VGPR-resident), W1 pack
// fragments and W2 relabel-pack fragments, compute G tiles for one gate.
// sfh/sfl: [4 jt][2 ic]; returns G acc for NBT b-tiles starting at bt0.
template <int NBT>
DEV void gate_compute(const bf16x8 sfh[4][2], const bf16x8 sfl[4][2],
                      const unsigned short* w1h_buf,
                      const unsigned short* w1l_buf,
                      const unsigned short* w2h_buf,
                      const unsigned short* w2l_buf, int ab, int bt0, int lane,
                      f32x4 G[NBT]) {
  const f32x4 zf = {0.f, 0.f, 0.f, 0.f};
  // matmul1': V[jt] = T^T tile (rows j = jt*16+4q+r, cols a = ab*16 + c)
  f32x4 V[4];
#pragma unroll
  for (int jt = 0; jt < 4; ++jt) V[jt] = zf;
#pragma unroll
  for (int ic = 0; ic < 2; ++ic) {
    bf16x8 w1h = ldpk(w1h_buf, ab * 2 + ic, lane);
    bf16x8 w1l = ldpk(w1l_buf, ab * 2 + ic, lane);
#pragma unroll
    for (int jt = 0; jt < 4; ++jt) {
      V[jt] = MFMA32(sfh[jt][ic], w1h, V[jt], 0, 0, 0);
      V[jt] = MFMA32(sfl[jt][ic], w1h, V[jt], 0, 0, 0);
      V[jt] = MFMA32(sfh[jt][ic], w1l, V[jt], 0, 0, 0);
    }
  }
  // in-register split to bf16 A-frags (k-slot relabeled; see pkB layout)
  unsigned int ph[8], pl[8];
#pragma unroll
  for (int t = 0; t < 4; ++t) {
    ph[t * 2 + 0] = pk2(V[t][0], V[t][1]);
    ph[t * 2 + 1] = pk2(V[t][2], V[t][3]);
  }
#pragma unroll
  for (int t = 0; t < 4; ++t) {
    float h0 = __uint_as_float(ph[t * 2 + 0] << 16);
    float h1 = __uint_as_float(ph[t * 2 + 0] & 0xFFFF0000u);
    float h2 = __uint_as_float(ph[t * 2 + 1] << 16);
    float h3 = __uint_as_float(ph[t * 2 + 1] & 0xFFFF0000u);
    pl[t * 2 + 0] = pk2(V[t][0] - h0, V[t][1] - h1);
    pl[t * 2 + 1] = pk2(V[t][2] - h2, V[t][3] - h3);
  }
  bf16x8 Th[2], Tl[2];
#pragma unroll
  for (int jc = 0; jc < 2; ++jc) {
    Th[jc] = frag4(ph[4 * jc], ph[4 * jc + 1], ph[4 * jc + 2], ph[4 * jc + 3]);
    Tl[jc] = frag4(pl[4 * jc], pl[4 * jc + 1], pl[4 * jc + 2], pl[4 * jc + 3]);
  }
  // matmul2: G[bt] (rows a = ab*16+4q+r, cols b = bt*16+c)
#pragma unroll
  for (int bi = 0; bi < NBT; ++bi) {
    G[bi] = zf;
#pragma unroll
    for (int jc = 0; jc < 2; ++jc) {
      bf16x8 w2h = ldpk(w2h_buf, (bt0 + bi) * 2 + jc, lane);
      bf16x8 w2l = ldpk(w2l_buf, (bt0 + bi) * 2 + jc, lane);
      G[bi] = MFMA32(Th[jc], w2h, G[bi], 0, 0, 0);
      G[bi] = MFMA32(Tl[jc], w2h, G[bi], 0, 0, 0);
      G[bi] = MFMA32(Th[jc], w2l, G[bi], 0, 0, 0);
    }
  }
}

// ---- phase 1: xg in fragment layout ------------------------------------------
// xg_f[l][g][n][w''(16)][lane(64)][r(4)] f32; w'' = ab*4 + bt;
// value = xg at (a = ab*16 + 4q + r, b = bt*16 + c)
__global__ __launch_bounds__(256, 2) void xg2_kernel(
    const float* __restrict__ x, const unsigned short* __restrict__ pkA,
    const unsigned short* __restrict__ pkB, float* __restrict__ xg) {
  __shared__ unsigned short xS0[4096], xS1[4096];
  const int n = blockIdx.x, l = blockIdx.y;
  const int tid = threadIdx.x;
  const int lane = tid & 63, ab = tid >> 6;
  const int c = lane & 15;

  // stage x(n,l) split into col-major swizzled LDS (verified R3 pattern)
  const float* xp = x + (((size_t)n * 128 + l) << 12);
  for (int i = tid; i < 1024; i += 256) {
    float4 v = ((const float4*)xp)[i];
    int row = i >> 4, cb = (i & 15) * 4;
    float vv[4] = {v.x, v.y, v.z, v.w};
#pragma unroll
    for (int j = 0; j < 4; ++j) {
      unsigned short hi, lo;
      split_bf(vv[j], hi, lo);
      int byte = ((cb + j) * 128 + row * 2) ^ (((cb + j) & 7) << 4);
      *(unsigned short*)((char*)xS0 + byte) = hi;
      *(unsigned short*)((char*)xS1 + byte) = lo;
    }
  }
  __syncthreads();

  // x^T fragments (VGPR, reused across gates)
  bf16x8 xfh[4][2], xfl[4][2];
#pragma unroll
  for (int jt = 0; jt < 4; ++jt)
#pragma unroll
    for (int ic = 0; ic < 2; ++ic) {
      xfh[jt][ic] = ldB(xS0, jt * 16 + c, ic * 32 + (lane >> 4) * 8);
      xfl[jt][ic] = ldB(xS1, jt * 16 + c, ic * 32 + (lane >> 4) * 8);
    }

  for (int g = 0; g < 3; ++g) {
    f32x4 G[4];
    gate_compute<4>(xfh, xfl, pkA + (g * 2 + 0) * 4096,
                    pkA + (g * 2 + 1) * 4096, pkB + (g * 2 + 0) * 4096,
                    pkB + (g * 2 + 1) * 4096, ab, 0, lane, G);
    float* xo =
        xg + ((((size_t)l * 3 + g) * 64 + n) * 16 + ab * 4) * 256 + lane * 4;
#pragma unroll
    for (int bt = 0; bt < 4; ++bt)
      *(f32x4*)(xo + (size_t)bt * 256) = G[bt];
  }
}

// ---- phase 2: per-n persistent recurrence ------------------------------------
__global__ __launch_bounds__(512, 2) void rec2_kernel(
    const unsigned short* __restrict__ pkA,
    const unsigned short* __restrict__ pkB, const float* __restrict__ xg,
    float* __restrict__ out) {
  __shared__ unsigned short u1s[6 * 4096];      // Wu1 x32 frags hi/lo  (48KB)
  __shared__ unsigned short u2s[6 * 4096];      // Wu2 relabel frags    (48KB)
  __shared__ unsigned short hS[2][2][4096];     // h^T split, dbuf      (32KB)
  const int n = blockIdx.x, tid = threadIdx.x;
  const int lane = tid & 63, wave = tid >> 6;
  const int ab = wave >> 1, bh = wave & 1;  // a-quarter, b-half
  const int q = lane >> 4, c = lane & 15;

  {  // stage Wu1/Wu2 fragment packs; zero h buffer 0
    const float4* s1 = (const float4*)(pkA + 24576);
    const float4* s2 = (const float4*)(pkB + 24576);
    float4* d1 = (float4*)u1s;
    float4* d2 = (float4*)u2s;
    for (int i = tid; i < 3072; i += 512) { d1[i] = s1[i]; d2[i] = s2[i]; }
    for (int i = tid; i < 2048; i += 512) {
      ((unsigned int*)hS[0][0])[i] = 0;
      ((unsigned int*)hS[0][1])[i] = 0;
    }
  }
  __syncthreads();

  float cst[2][4] = {}, zst[2][4], hn[2][4] = {};

#pragma unroll 1
  for (int l = 0; l < 128; ++l) {
    const int p = l & 1;
    // prefetch xg fragments (coalesced float4)
    f32x4 xv[3][2];
#pragma unroll
    for (int g = 0; g < 3; ++g)
#pragma unroll
      for (int bi = 0; bi < 2; ++bi)
        xv[g][bi] = *(const f32x4*)(
            xg + ((((size_t)l * 3 + g) * 64 + n) * 16 + ab * 4 + bh * 2 + bi) *
                     256 +
            lane * 4);
    // h^T fragments (VGPR, reused across 3 gates)
    bf16x8 hfh[4][2], hfl[4][2];
#pragma unroll
    for (int jt = 0; jt < 4; ++jt)
#pragma unroll
      for (int ic = 0; ic < 2; ++ic) {
        hfh[jt][ic] = ldB(hS[p][0], jt * 16 + c, ic * 32 + q * 8);
        hfl[jt][ic] = ldB(hS[p][1], jt * 16 + c, ic * 32 + q * 8);
      }

#pragma unroll
    for (int g = 0; g < 3; ++g) {
      f32x4 G[2];
      gate_compute<2>(hfh, hfl, u1s + (g * 2 + 0) * 4096,
                      u1s + (g * 2 + 1) * 4096, u2s + (g * 2 + 0) * 4096,
                      u2s + (g * 2 + 1) * 4096, ab, bh * 2, lane, G);
      if (g == 0) {
#pragma unroll
        for (int bi = 0; bi < 2; ++bi)
#pragma unroll
          for (int r = 0; r < 4; ++r)
            zst[bi][r] = sigf(G[bi][r] + xv[0][bi][r]);
      } else if (g == 1) {
#pragma unroll
        for (int bi = 0; bi < 2; ++bi)
#pragma unroll
          for (int r = 0; r < 4; ++r) {
            float rr = sigf(G[bi][r] + xv[1][bi][r]);
            cst[bi][r] = rr * (cst[bi][r] + zst[bi][r]);  // c = r*c + z*r
          }
      } else {
        float* op = out + (((size_t)n * 128 + l) << 12);
#pragma unroll
        for (int bi = 0; bi < 2; ++bi) {
          unsigned short hh[4], hl[4];
#pragma unroll
          for (int r = 0; r < 4; ++r) {
            float o = sigf(G[bi][r] + xv[2][bi][r]);
            hn[bi][r] = o * sigf(cst[bi][r]);
            split_bf(hn[bi][r], hh[r], hl[r]);
            op[(ab * 16 + q * 4 + r) * 64 + (bh * 2 + bi) * 16 + c] =
                hn[bi][r];
          }
          stB4(hS[p ^ 1][0], (bh * 2 + bi) * 16 + c, ab * 16 + q * 4, hh);
          stB4(hS[p ^ 1][1], (bh * 2 + bi) * 16 + c, ab * 16 + q * 4, hl);
        }
      }
    }
    __syncthreads();  // new h visible for next step
  }
  // h_last, c_last
  float* hl_ = out + 33554432 + ((size_t)n << 12);
  float* cl_ = hl_ + 262144;
#pragma unroll
  for (int bi = 0; bi < 2; ++bi)
#pragma unroll
    for (int r = 0; r < 4; ++r) {
      int off = (ab * 16 + q * 4 + r) * 64 + (bh * 2 + bi) * 16 + c;
      hl_[off] = hn[bi][r];
      cl_[off] = cst[bi][r];
    }
}

// ---- fallback (ws too small): f32 VALU path (verified R1) --------------------
DEV void ld4(float v[4], const float* p) {
  float4 t = *(const float4*)p;
  v[0] = t.x; v[1] = t.y; v[2] = t.z; v[3] = t.w;
}
DEV void mm_acc(float acc[4][4], const float* A, const float* B, int a0, int b0) {
#pragma unroll 8
  for (int k = 0; k < 64; ++k) {
    float av[4], bv[4];
    ld4(av, A + k * 64 + a0);
    ld4(bv, B + k * 64 + b0);
#pragma unroll
    for (int r = 0; r < 4; ++r)
#pragma unroll
      for (int cc = 0; cc < 4; ++cc)
        acc[r][cc] = __fmaf_rn(av[r], bv[cc], acc[r][cc]);
  }
}
DEV void wr_tt(float* Tt, const float acc[4][4], int a0, int b0) {
#pragma unroll
  for (int cc = 0; cc < 4; ++cc)
    *(float4*)(Tt + (b0 + cc) * 64 + a0) =
        make_float4(acc[0][cc], acc[1][cc], acc[2][cc], acc[3][cc]);
}
__global__ __launch_bounds__(256) void wtrans_kernel(
    const float* __restrict__ Ww1, const float* __restrict__ Ww2,
    const float* __restrict__ Wu1, const float* __restrict__ Wu2,
    float* __restrict__ o) {
  int b = blockIdx.x;
  int mat = b / 3, g = b % 3;
  const float* src =
      (mat == 0 ? Ww1 : mat == 1 ? Ww2 : mat == 2 ? Wu1 : Wu2) + g * 4096;
  float* dst = o + b * 4096;
  for (int e = threadIdx.x; e < 4096; e += 256) {
    int a = e >> 6, i = e & 63;
    dst[i * 64 + a] = src[a * 64 + i];
  }
}
__global__ __launch_bounds__(256) void rec_fb_kernel(
    const float* __restrict__ WT, const float* __restrict__ inputs,
    float* __restrict__ out) {
  __shared__ float hs[4096];
  __shared__ float Tt[4096];
  __shared__ float xt[4096];
  const int n = blockIdx.x;
  const int tid = threadIdx.x;
  const int a0 = (tid >> 4) << 2;
  const int b0 = (tid & 15) << 2;
  float creg[4][4] = {}, zreg[4][4], hnew[4][4] = {};
  for (int e = tid; e < 4096; e += 256) hs[e] = 0.0f;
  __syncthreads();
  for (int l = 0; l < 128; ++l) {
    const float4* src = (const float4*)(inputs + (((size_t)n * 128 + l) << 12));
#pragma unroll
    for (int e = 0; e < 4; ++e)
      ((float4*)xt)[tid + 256 * e] = src[tid + 256 * e];
    __syncthreads();
    for (int g = 0; g < 3; ++g) {
      float gv[4][4] = {};
      float accx[4][4] = {};
      mm_acc(accx, WT + g * 4096, xt, a0, b0);
      wr_tt(Tt, accx, a0, b0);
      __syncthreads();
      mm_acc(gv, Tt, WT + (3 + g) * 4096, a0, b0);
      __syncthreads();
      float acc[4][4] = {};
      mm_acc(acc, WT + (6 + g) * 4096, hs, a0, b0);
      wr_tt(Tt, acc, a0, b0);
      __syncthreads();
      mm_acc(gv, Tt, WT + (9 + g) * 4096, a0, b0);
      if (g == 0) {
#pragma unroll
        for (int r = 0; r < 4; ++r)
#pragma unroll
          for (int cc = 0; cc < 4; ++cc) zreg[r][cc] = sigf(gv[r][cc]);
      } else if (g == 1) {
#pragma unroll
        for (int r = 0; r < 4; ++r)
#pragma unroll
          for (int cc = 0; cc < 4; ++cc) {
            float rr = sigf(gv[r][cc]);
            creg[r][cc] = rr * (creg[r][cc] + zreg[r][cc]);
          }
      } else {
        float* op = out + (((size_t)n * 128 + l) << 12);
#pragma unroll
        for (int r = 0; r < 4; ++r) {
#pragma unroll
          for (int cc = 0; cc < 4; ++cc)
            hnew[r][cc] = sigf(gv[r][cc]) * sigf(creg[r][cc]);
          float4 v = make_float4(hnew[r][0], hnew[r][1], hnew[r][2], hnew[r][3]);
          *(float4*)(hs + (a0 + r) * 64 + b0) = v;
          *(float4*)(op + (a0 + r) * 64 + b0) = v;
        }
      }
      __syncthreads();
    }
  }
  float* hl = out + 33554432 + ((size_t)n << 12);
  float* cl = hl + 262144;
#pragma unroll
  for (int r = 0; r < 4; ++r) {
    *(float4*)(hl + (a0 + r) * 64 + b0) =
        make_float4(hnew[r][0], hnew[r][1], hnew[r][2], hnew[r][3]);
    *(float4*)(cl + (a0 + r) * 64 + b0) =
        make_float4(creg[r][0], creg[r][1], creg[r][2], creg[r][3]);
  }
}

extern "C" void kernel_launch(void* const* d_in, const int* in_sizes, int n_in,
                              void* d_out, int out_size, void* d_ws,
                              size_t ws_size, hipStream_t stream) {
  (void)in_sizes; (void)n_in; (void)out_size;
  const float* inputs = (const float*)d_in[0];
  const float* Ww1 = (const float*)d_in[1];
  const float* Ww2 = (const float*)d_in[2];
  const float* Wu1 = (const float*)d_in[3];
  const float* Wu2 = (const float*)d_in[4];
  float* out = (float*)d_out;
  char* ws = (char*)d_ws;
  const size_t PKB_OFF = 98304;             // pkA: 12*4096 shorts
  const size_t XG_OFF = 262144;             // pkB: 12*4096 shorts
  const size_t XG_F32 = (size_t)128 * 3 * 64 * 4096 * 4;  // 402,653,184 B

  if (ws_size >= XG_OFF + XG_F32) {
    unsigned short* pkA = (unsigned short*)ws;
    unsigned short* pkB = (unsigned short*)(ws + PKB_OFF);
    float* xg = (float*)(ws + XG_OFF);
    pack2_kernel<<<dim3(24), dim3(256), 0, stream>>>(Ww1, Ww2, Wu1, Wu2, pkA,
                                                     pkB);
    xg2_kernel<<<dim3(64, 128), dim3(256), 0, stream>>>(inputs, pkA, pkB, xg);
    rec2_kernel<<<dim3(64), dim3(512), 0, stream>>>(pkA, pkB, xg, out);
  } else {
    float* WT = (float*)ws;
    wtrans_kernel<<<dim3(12), dim3(256), 0, stream>>>(Ww1, Ww2, Wu1, Wu2, WT);
    rec_fb_kernel<<<dim3(64), dim3(256), 0, stream>>>(WT, inputs, out);
  }
}

// Round 8
// 714.619 us; speedup vs baseline: 8.7196x; 1.2998x over previous
//
#include <hip/hip_runtime.h>
#include <hip/hip_bf16.h>
#include <cstddef>

#define DEV static __device__ __forceinline__

typedef __attribute__((ext_vector_type(8))) short bf16x8;
typedef __attribute__((ext_vector_type(4))) float f32x4;

#define MFMA32 __builtin_amdgcn_mfma_f32_16x16x32_bf16

DEV float sigf(float x) { return 1.0f / (1.0f + __expf(-x)); }

DEV unsigned short f2bf(float f) {
  unsigned int u = __float_as_uint(f);
  u = (u + 0x7FFFu + ((u >> 16) & 1u)) >> 16;
  return (unsigned short)u;
}
// pack two f32 -> bf16x2 (lo in low 16 bits)
DEV unsigned int pk2(float lo, float hi) {
  __hip_bfloat162 t = __float22bfloat162_rn(make_float2(lo, hi));
  union { __hip_bfloat162 h; unsigned int u; } x;
  x.h = t;
  return x.u;
}
DEV float bflo(unsigned int u) { return __uint_as_float(u << 16); }
DEV float bfhi(unsigned int u) { return __uint_as_float(u & 0xFFFF0000u); }
DEV bf16x8 frag4(unsigned int a, unsigned int b, unsigned int c,
                 unsigned int d) {
  union { unsigned int u[4]; bf16x8 v; } x;
  x.u[0] = a; x.u[1] = b; x.u[2] = c; x.u[3] = d;
  return x.v;
}

// packed-fragment load: 16B per lane (global or LDS)
DEV bf16x8 ldpk(const unsigned short* buf, int chunk, int lane) {
  return *(const bf16x8*)(buf + (chunk * 64 + lane) * 8);
}
// col-major XOR-swizzled LDS buffer: element (k, col) at byte col*128+k*2
DEV bf16x8 ldB(const unsigned short* buf, int col, int k0) {
  int byte = (col * 128 + k0 * 2) ^ ((col & 7) << 4);
  return *(const bf16x8*)((const char*)buf + byte);
}
DEV void stBu1(unsigned short* buf, int col, int k_even, unsigned int v) {
  int byte = (col * 128 + k_even * 2) ^ ((col & 7) << 4);
  *(unsigned int*)((char*)buf + byte) = v;
}
DEV void stBu2(unsigned short* buf, int col, int k0, unsigned int v0,
               unsigned int v1) {
  int byte = (col * 128 + k0 * 2) ^ ((col & 7) << 4);
  *(uint2*)((char*)buf + byte) = make_uint2(v0, v1);
}

// ---- pack kernel (bf16 hi only) ---------------------------------------------
// pkA: b = m3*3+g (m3: 0=Ww1, 1=Wu1), x32 frag layout:
//   chunk rb*2+kc, lane l, j: W[rb*16 + (l&15)][kc*32 + (l>>4)*8 + j]
// pkB: b = m3*3+g (m3: 0=Ww2, 1=Wu2), relabeled for matmul2 B-operand:
//   chunk bt*2+jc, lane l, jj: W[bt*16 + (l&15)][32*jc + 16*(jj>>2) + 4*(l>>4) + (jj&3)]
__global__ __launch_bounds__(256) void pack3_kernel(
    const float* __restrict__ Ww1, const float* __restrict__ Ww2,
    const float* __restrict__ Wu1, const float* __restrict__ Wu2,
    unsigned short* __restrict__ pkA, unsigned short* __restrict__ pkB) {
  int b = blockIdx.x;  // 0..11
  if (b < 6) {
    const float* src = (b < 3 ? Ww1 : Wu1) + (b % 3) * 4096;
    unsigned short* dst = pkA + b * 4096;
    for (int idx = threadIdx.x; idx < 4096; idx += 256) {
      int chunk = idx >> 9, lane = (idx >> 3) & 63, jj = idx & 7;
      int row = (chunk >> 1) * 16 + (lane & 15);
      int k = (chunk & 1) * 32 + (lane >> 4) * 8 + jj;
      dst[idx] = f2bf(src[row * 64 + k]);
    }
  } else {
    int bb = b - 6;
    const float* src = (bb < 3 ? Ww2 : Wu2) + (bb % 3) * 4096;
    unsigned short* dst = pkB + bb * 4096;
    for (int idx = threadIdx.x; idx < 4096; idx += 256) {
      int chunk = idx >> 9, lane = (idx >> 3) & 63, jj = idx & 7;
      int bcol = (chunk >> 1) * 16 + (lane & 15);
      int j = 32 * (chunk & 1) + 16 * (jj >> 2) + 4 * (lane >> 4) + (jj & 3);
      dst[idx] = f2bf(src[bcol * 64 + j]);
    }
  }
}

// ---- phase 1: xg packed-bf16, rec-fragment order -----------------------------
// layout: [l][n][tid'(512)][g(3)][bi(2)][r(4)] bf16 ; 24 ushort per thread
__global__ __launch_bounds__(256) void xg3_kernel(
    const float* __restrict__ x, const unsigned short* __restrict__ pkA,
    const unsigned short* __restrict__ pkB, unsigned short* __restrict__ xgp) {
  __shared__ unsigned short xS[4096];
  const int n = blockIdx.x, l = blockIdx.y;
  const int tid = threadIdx.x;
  const int lane = tid & 63, ab = tid >> 6;
  const int q = lane >> 4, c = lane & 15;
  const f32x4 zf = {0.f, 0.f, 0.f, 0.f};

  // stage x(n,l)^T as bf16, col-major swizzled; row-pairs -> packed u32 writes
  const float* xp = x + (((size_t)n * 128 + l) << 12);
#pragma unroll
  for (int k = 0; k < 2; ++k) {
    int u = tid * 2 + k;
    int rp = u >> 4, j4 = (u & 15) * 4;
    const float* bse = xp + (2 * rp) * 64 + j4;
    float4 v0 = *(const float4*)bse;
    float4 v1 = *(const float4*)(bse + 64);
    float a0[4] = {v0.x, v0.y, v0.z, v0.w};
    float a1[4] = {v1.x, v1.y, v1.z, v1.w};
#pragma unroll
    for (int jj = 0; jj < 4; ++jj)
      stBu1(xS, j4 + jj, 2 * rp, pk2(a0[jj], a1[jj]));
  }
  __syncthreads();

  // x^T fragments
  bf16x8 xf[4][2];
#pragma unroll
  for (int jt = 0; jt < 4; ++jt)
#pragma unroll
    for (int ic = 0; ic < 2; ++ic)
      xf[jt][ic] = ldB(xS, jt * 16 + c, ic * 32 + q * 8);

  const size_t blk = ((size_t)l * 64 + n) * 512;
#pragma unroll
  for (int g = 0; g < 3; ++g) {
    f32x4 V[4];
#pragma unroll
    for (int jt = 0; jt < 4; ++jt) V[jt] = zf;
#pragma unroll
    for (int ic = 0; ic < 2; ++ic) {
      bf16x8 w1 = ldpk(pkA + g * 4096, ab * 2 + ic, lane);
#pragma unroll
      for (int jt = 0; jt < 4; ++jt)
        V[jt] = MFMA32(xf[jt][ic], w1, V[jt], 0, 0, 0);
    }
    unsigned int ph[8];
#pragma unroll
    for (int t = 0; t < 4; ++t) {
      ph[t * 2 + 0] = pk2(V[t][0], V[t][1]);
      ph[t * 2 + 1] = pk2(V[t][2], V[t][3]);
    }
    bf16x8 Th0 = frag4(ph[0], ph[1], ph[2], ph[3]);
    bf16x8 Th1 = frag4(ph[4], ph[5], ph[6], ph[7]);
#pragma unroll
    for (int bt = 0; bt < 4; ++bt) {
      f32x4 G = zf;
      G = MFMA32(Th0, ldpk(pkB + g * 4096, bt * 2 + 0, lane), G, 0, 0, 0);
      G = MFMA32(Th1, ldpk(pkB + g * 4096, bt * 2 + 1, lane), G, 0, 0, 0);
      int tidp = (ab * 2 + (bt >> 1)) * 64 + lane;
      unsigned short* dst =
          xgp + (blk + tidp) * 24 + g * 8 + (bt & 1) * 4;
      *(uint2*)dst = make_uint2(pk2(G[0], G[1]), pk2(G[2], G[3]));
    }
  }
}

// ---- phase 2: per-n persistent recurrence, 1-term bf16, weights in VGPR ------
__global__ __launch_bounds__(512, 2) void rec3_kernel(
    const unsigned short* __restrict__ pkA,
    const unsigned short* __restrict__ pkB,
    const unsigned short* __restrict__ xgp, float* __restrict__ out) {
  __shared__ unsigned short hS[2][4096];  // h^T bf16, dbuf, swizzled (16KB)
  const int n = blockIdx.x, tid = threadIdx.x;
  const int lane = tid & 63, wave = tid >> 6;
  const int ab = wave >> 1, bh = wave & 1;
  const int q = lane >> 4, c = lane & 15;
  const f32x4 zf = {0.f, 0.f, 0.f, 0.f};

  // hoist all weight fragments into VGPRs (l-invariant)
  bf16x8 w1f[3][2], w2f[3][2][2];
#pragma unroll
  for (int g = 0; g < 3; ++g) {
#pragma unroll
    for (int ic = 0; ic < 2; ++ic)
      w1f[g][ic] = ldpk(pkA + (3 + g) * 4096, ab * 2 + ic, lane);
#pragma unroll
    for (int bi = 0; bi < 2; ++bi)
#pragma unroll
      for (int jc = 0; jc < 2; ++jc)
        w2f[g][bi][jc] =
            ldpk(pkB + (3 + g) * 4096, (bh * 2 + bi) * 2 + jc, lane);
  }
  for (int i = tid; i < 2048; i += 512) ((unsigned int*)hS[0])[i] = 0;
  __syncthreads();

  float cst[2][4] = {}, zst[2][4], hn[2][4] = {};
  const unsigned short* xbase = xgp + ((size_t)n * 512 + tid) * 24;
  uint4 xc[3];
  {
    const uint4* p0 = (const uint4*)xbase;
    xc[0] = p0[0]; xc[1] = p0[1]; xc[2] = p0[2];
  }

#pragma unroll 1
  for (int l = 0; l < 128; ++l) {
    const int p = l & 1;
    // h^T fragments for this step
    bf16x8 hf[4][2];
#pragma unroll
    for (int jt = 0; jt < 4; ++jt)
#pragma unroll
      for (int ic = 0; ic < 2; ++ic)
        hf[jt][ic] = ldB(hS[p], jt * 16 + c, ic * 32 + q * 8);
    // prefetch next step's xg (hides HBM/L3 latency under 3 gates)
    uint4 xn[3];
    if (l < 127) {
      const uint4* pn =
          (const uint4*)(xbase + (size_t)(l + 1) * 64 * 512 * 24);
      xn[0] = pn[0]; xn[1] = pn[1]; xn[2] = pn[2];
    }

#pragma unroll
    for (int g = 0; g < 3; ++g) {
      f32x4 V[4];
#pragma unroll
      for (int jt = 0; jt < 4; ++jt) V[jt] = zf;
#pragma unroll
      for (int ic = 0; ic < 2; ++ic)
#pragma unroll
        for (int jt = 0; jt < 4; ++jt)
          V[jt] = MFMA32(hf[jt][ic], w1f[g][ic], V[jt], 0, 0, 0);
      unsigned int ph[8];
#pragma unroll
      for (int t = 0; t < 4; ++t) {
        ph[t * 2 + 0] = pk2(V[t][0], V[t][1]);
        ph[t * 2 + 1] = pk2(V[t][2], V[t][3]);
      }
      bf16x8 Th0 = frag4(ph[0], ph[1], ph[2], ph[3]);
      bf16x8 Th1 = frag4(ph[4], ph[5], ph[6], ph[7]);
      f32x4 G[2];
#pragma unroll
      for (int bi = 0; bi < 2; ++bi) {
        G[bi] = zf;
        G[bi] = MFMA32(Th0, w2f[g][bi][0], G[bi], 0, 0, 0);
        G[bi] = MFMA32(Th1, w2f[g][bi][1], G[bi], 0, 0, 0);
      }
      // unpack xg for this gate
      uint4 X = xc[g];
      float xv[2][4];
      xv[0][0] = bflo(X.x); xv[0][1] = bfhi(X.x);
      xv[0][2] = bflo(X.y); xv[0][3] = bfhi(X.y);
      xv[1][0] = bflo(X.z); xv[1][1] = bfhi(X.z);
      xv[1][2] = bflo(X.w); xv[1][3] = bfhi(X.w);
      if (g == 0) {
#pragma unroll
        for (int bi = 0; bi < 2; ++bi)
#pragma unroll
          for (int r = 0; r < 4; ++r)
            zst[bi][r] = sigf(G[bi][r] + xv[bi][r]);
      } else if (g == 1) {
#pragma unroll
        for (int bi = 0; bi < 2; ++bi)
#pragma unroll
          for (int r = 0; r < 4; ++r) {
            float rr = sigf(G[bi][r] + xv[bi][r]);
            cst[bi][r] = rr * (cst[bi][r] + zst[bi][r]);  // c = r*c + z*r
          }
      } else {
        float* op = out + (((size_t)n * 128 + l) << 12);
#pragma unroll
        for (int bi = 0; bi < 2; ++bi) {
#pragma unroll
          for (int r = 0; r < 4; ++r) {
            float o = sigf(G[bi][r] + xv[bi][r]);
            hn[bi][r] = o * sigf(cst[bi][r]);
            op[(ab * 16 + q * 4 + r) * 64 + (bh * 2 + bi) * 16 + c] =
                hn[bi][r];
          }
          stBu2(hS[p ^ 1], (bh * 2 + bi) * 16 + c, ab * 16 + q * 4,
                pk2(hn[bi][0], hn[bi][1]), pk2(hn[bi][2], hn[bi][3]));
        }
      }
    }
    if (l < 127) { xc[0] = xn[0]; xc[1] = xn[1]; xc[2] = xn[2]; }
    __syncthreads();
  }
  float* hl_ = out + 33554432 + ((size_t)n << 12);
  float* cl_ = hl_ + 262144;
#pragma unroll
  for (int bi = 0; bi < 2; ++bi)
#pragma unroll
    for (int r = 0; r < 4; ++r) {
      int off = (ab * 16 + q * 4 + r) * 64 + (bh * 2 + bi) * 16 + c;
      hl_[off] = hn[bi][r];
      cl_[off] = cst[bi][r];
    }
}

// ---- fallback (ws too small): f32 VALU path (verified R1) --------------------
DEV void ld4(float v[4], const float* p) {
  float4 t = *(const float4*)p;
  v[0] = t.x; v[1] = t.y; v[2] = t.z; v[3] = t.w;
}
DEV void mm_acc(float acc[4][4], const float* A, const float* B, int a0, int b0) {
#pragma unroll 8
  for (int k = 0; k < 64; ++k) {
    float av[4], bv[4];
    ld4(av, A + k * 64 + a0);
    ld4(bv, B + k * 64 + b0);
#pragma unroll
    for (int r = 0; r < 4; ++r)
#pragma unroll
      for (int cc = 0; cc < 4; ++cc)
        acc[r][cc] = __fmaf_rn(av[r], bv[cc], acc[r][cc]);
  }
}
DEV void wr_tt(float* Tt, const float acc[4][4], int a0, int b0) {
#pragma unroll
  for (int cc = 0; cc < 4; ++cc)
    *(float4*)(Tt + (b0 + cc) * 64 + a0) =
        make_float4(acc[0][cc], acc[1][cc], acc[2][cc], acc[3][cc]);
}
__global__ __launch_bounds__(256) void wtrans_kernel(
    const float* __restrict__ Ww1, const float* __restrict__ Ww2,
    const float* __restrict__ Wu1, const float* __restrict__ Wu2,
    float* __restrict__ o) {
  int b = blockIdx.x;
  int mat = b / 3, g = b % 3;
  const float* src =
      (mat == 0 ? Ww1 : mat == 1 ? Ww2 : mat == 2 ? Wu1 : Wu2) + g * 4096;
  float* dst = o + b * 4096;
  for (int e = threadIdx.x; e < 4096; e += 256) {
    int a = e >> 6, i = e & 63;
    dst[i * 64 + a] = src[a * 64 + i];
  }
}
__global__ __launch_bounds__(256) void rec_fb_kernel(
    const float* __restrict__ WT, const float* __restrict__ inputs,
    float* __restrict__ out) {
  __shared__ float hs[4096];
  __shared__ float Tt[4096];
  __shared__ float xt[4096];
  const int n = blockIdx.x;
  const int tid = threadIdx.x;
  const int a0 = (tid >> 4) << 2;
  const int b0 = (tid & 15) << 2;
  float creg[4][4] = {}, zreg[4][4], hnew[4][4] = {};
  for (int e = tid; e < 4096; e += 256) hs[e] = 0.0f;
  __syncthreads();
  for (int l = 0; l < 128; ++l) {
    const float4* src = (const float4*)(inputs + (((size_t)n * 128 + l) << 12));
#pragma unroll
    for (int e = 0; e < 4; ++e)
      ((float4*)xt)[tid + 256 * e] = src[tid + 256 * e];
    __syncthreads();
    for (int g = 0; g < 3; ++g) {
      float gv[4][4] = {};
      float accx[4][4] = {};
      mm_acc(accx, WT + g * 4096, xt, a0, b0);
      wr_tt(Tt, accx, a0, b0);
      __syncthreads();
      mm_acc(gv, Tt, WT + (3 + g) * 4096, a0, b0);
      __syncthreads();
      float acc[4][4] = {};
      mm_acc(acc, WT + (6 + g) * 4096, hs, a0, b0);
      wr_tt(Tt, acc, a0, b0);
      __syncthreads();
      mm_acc(gv, Tt, WT + (9 + g) * 4096, a0, b0);
      if (g == 0) {
#pragma unroll
        for (int r = 0; r < 4; ++r)
#pragma unroll
          for (int cc = 0; cc < 4; ++cc) zreg[r][cc] = sigf(gv[r][cc]);
      } else if (g == 1) {
#pragma unroll
        for (int r = 0; r < 4; ++r)
#pragma unroll
          for (int cc = 0; cc < 4; ++cc) {
            float rr = sigf(gv[r][cc]);
            creg[r][cc] = rr * (creg[r][cc] + zreg[r][cc]);
          }
      } else {
        float* op = out + (((size_t)n * 128 + l) << 12);
#pragma unroll
        for (int r = 0; r < 4; ++r) {
#pragma unroll
          for (int cc = 0; cc < 4; ++cc)
            hnew[r][cc] = sigf(gv[r][cc]) * sigf(creg[r][cc]);
          float4 v = make_float4(hnew[r][0], hnew[r][1], hnew[r][2], hnew[r][3]);
          *(float4*)(hs + (a0 + r) * 64 + b0) = v;
          *(float4*)(op + (a0 + r) * 64 + b0) = v;
        }
      }
      __syncthreads();
    }
  }
  float* hl = out + 33554432 + ((size_t)n << 12);
  float* cl = hl + 262144;
#pragma unroll
  for (int r = 0; r < 4; ++r) {
    *(float4*)(hl + (a0 + r) * 64 + b0) =
        make_float4(hnew[r][0], hnew[r][1], hnew[r][2], hnew[r][3]);
    *(float4*)(cl + (a0 + r) * 64 + b0) =
        make_float4(creg[r][0], creg[r][1], creg[r][2], creg[r][3]);
  }
}

extern "C" void kernel_launch(void* const* d_in, const int* in_sizes, int n_in,
                              void* d_out, int out_size, void* d_ws,
                              size_t ws_size, hipStream_t stream) {
  (void)in_sizes; (void)n_in; (void)out_size;
  const float* inputs = (const float*)d_in[0];
  const float* Ww1 = (const float*)d_in[1];
  const float* Ww2 = (const float*)d_in[2];
  const float* Wu1 = (const float*)d_in[3];
  const float* Wu2 = (const float*)d_in[4];
  float* out = (float*)d_out;
  char* ws = (char*)d_ws;
  const size_t PKB_OFF = 49152;   // pkA: 6*4096 ushorts
  const size_t XG_OFF = 131072;   // pkB: 6*4096 ushorts (+pad)
  const size_t XG_BF = (size_t)128 * 64 * 512 * 24 * 2;  // 201,326,592 B

  if (ws_size >= XG_OFF + XG_BF) {
    unsigned short* pkA = (unsigned short*)ws;
    unsigned short* pkB = (unsigned short*)(ws + PKB_OFF);
    unsigned short* xgp = (unsigned short*)(ws + XG_OFF);
    pack3_kernel<<<dim3(12), dim3(256), 0, stream>>>(Ww1, Ww2, Wu1, Wu2, pkA,
                                                     pkB);
    xg3_kernel<<<dim3(64, 128), dim3(256), 0, stream>>>(inputs, pkA, pkB, xgp);
    rec3_kernel<<<dim3(64), dim3(512), 0, stream>>>(pkA, pkB, xgp, out);
  } else {
    float* WT = (float*)ws;
    wtrans_kernel<<<dim3(12), dim3(256), 0, stream>>>(Ww1, Ww2, Wu1, Wu2, WT);
    rec_fb_kernel<<<dim3(64), dim3(256), 0, stream>>>(WT, inputs, out);
  }
}